// Round 6
// baseline (277.971 us; speedup 1.0000x reference)
//
#include <hip/hip_runtime.h>
#include <hip/hip_bf16.h>

#define IN_F   4096
#define OUT_F  4096
#define PACKED (IN_F / 8)      // 512
#define M_DIM  8192            // 4 * 2048
#define N_DIM  4096
#define K_DIM  4096

#define BM 256
#define BN 256
#define BK 64
#define NT (K_DIM / BK)        // 64 K-tiles

typedef __bf16 bf16x8 __attribute__((ext_vector_type(8)));
typedef float  f32x4  __attribute__((ext_vector_type(4)));

#define BAR() asm volatile("s_barrier" ::: "memory")
#define VMCNT(n) asm volatile("s_waitcnt vmcnt(" #n ")" ::: "memory")

// ---------------------------------------------------------------------------
// Fragment-ordered DRAM layout for both GEMM operands (produced by prepasses):
//   [128-row-half][kTile(64)][subtile st(16)][1024 B]
//   subtile st: rows (st>>1)*16..+15 (within the half), cols (st&1)*32..+31
//   within subtile, chunk l (=byte/16): row16 = l&15, k8 = (l>>4)*8
// A wave staging a subtile reads a CONTIGUOUS 1 KB; ds_read_b128 fragment
// reads are lane-linear (0 bank conflicts).
// ---------------------------------------------------------------------------

// Pre-pass 1: dequantize int4 -> bf16 fragment-ordered W.
__global__ __launch_bounds__(256) void dequant_kernel(
    const int* __restrict__ qw, const float* __restrict__ qs,
    const int* __restrict__ qz, __bf16* __restrict__ W)
{
    int ch = blockIdx.x * blockDim.x + threadIdx.x;
    if (ch >= OUT_F * PACKED) return;
    int l     = ch & 63;
    int st    = (ch >> 6) & 15;
    int kTile = (ch >> 10) & 63;
    int nHalf = ch >> 16;
    int o  = nHalf * 128 + ((st >> 1) << 4) + (l & 15);
    int k0 = kTile * 64 + ((st & 1) << 5) + ((l >> 4) << 3);
    int g  = k0 >> 7;
    unsigned int q = (unsigned int)qw[o * PACKED + (k0 >> 3)];
    float scale = qs[g * OUT_F + o];
    float zero  = (float)qz[g * OUT_F + o];
    bf16x8 v;
#pragma unroll
    for (int i = 0; i < 8; ++i) {
        float wi = (float)((q >> (4 * i)) & 15u);
        v[i] = (__bf16)((wi - zero) * scale);
    }
    *reinterpret_cast<bf16x8*>(&W[(size_t)ch * 8]) = v;
}

// Pre-pass 2: x f32 -> bf16 fragment-ordered xb.
__global__ __launch_bounds__(256) void cvt_kernel(
    const float* __restrict__ x, __bf16* __restrict__ xb, int nch)
{
    int ch = blockIdx.x * blockDim.x + threadIdx.x;
    if (ch >= nch) return;
    int l     = ch & 63;
    int st    = (ch >> 6) & 15;
    int kTile = (ch >> 10) & 63;
    int mHalf = ch >> 16;
    int m  = mHalf * 128 + ((st >> 1) << 4) + (l & 15);
    int k0 = kTile * 64 + ((st & 1) << 5) + ((l >> 4) << 3);
    const float4* xv = reinterpret_cast<const float4*>(x + (size_t)m * K_DIM + k0);
    float4 a = xv[0];
    float4 b = xv[1];
    bf16x8 v;
    v[0] = (__bf16)a.x; v[1] = (__bf16)a.y; v[2] = (__bf16)a.z; v[3] = (__bf16)a.w;
    v[4] = (__bf16)b.x; v[5] = (__bf16)b.y; v[6] = (__bf16)b.z; v[7] = (__bf16)b.w;
    reinterpret_cast<bf16x8*>(xb)[ch] = v;
}

// ---------------------------------------------------------------------------
// GEMM: 256x256 tile, BK=64, 8 waves (2Mx4N), 4 phases/K-tile.
// Balanced reads 4/8/4/8; stage discipline: B one tile ahead (other buffer),
// A two tiles ahead (own buffer, after its last read phase).
//   p0: read B01(t);      stage B0(t+1); Q0 = A03*B01
//   p1: read A47(t);      stage B1(t+1); Q1 = A47*B01
//   p2: read B23(t);      stage A0(t+2); Q2 = A03*B23; VMCNT(6) [A(t+1) ready]
//   p3: read A03(t+1);    stage A1(t+2); Q3 = A47*B23; VMCNT(4) [B(t+1) ready]
// No same-tile write into a region with pending reads.
// ---------------------------------------------------------------------------
__global__ __launch_bounds__(512, 2) void gemm_kernel(
    const __bf16* __restrict__ A, const __bf16* __restrict__ B,
    float* __restrict__ C)
{
    extern __shared__ __bf16 lds[];   // 2 bufs x (A 16384 + B 16384) = 128 KiB

    const int tid  = threadIdx.x;
    const int lane = tid & 63;
    const int wave = tid >> 6;        // 0..7
    const int wm   = wave >> 2;       // 0..1
    const int wn   = wave & 3;        // 0..3

    // bijective XCD swizzle: 512 blocks = 8 XCDs x 64
    const int bid = blockIdx.x;
    const int swz = (bid & 7) * 64 + (bid >> 3);
    const int nBase = (swz & 15) * BN;
    const int mBase = (swz >> 4) * BM;
    const int mHalf0 = mBase >> 7;
    const int nHalf0 = nBase >> 7;

    const int lr = lane & 15;

    // stage one 128x64 half-tile (16 subtiles): 2 contiguous-1KB loads/thread
    auto stage_half = [&](const __bf16* __restrict__ srcFrag, __bf16* dstMat,
                          int halfGlobal, int kTile, int hh) {
#pragma unroll
        for (int i = 0; i < 2; ++i) {
            const int st = i * 8 + wave;          // wave-uniform
            const __bf16* base = srcFrag + ((size_t)(halfGlobal * 64 + kTile) << 13);
            __builtin_amdgcn_global_load_lds(
                (const __attribute__((address_space(1))) void*)(base + st * 512 + lane * 8),
                (__attribute__((address_space(3))) void*)(dstMat + (hh * 16 + st) * 512 + lane * 8),
                16, 0, 0);
        }
    };
    // h: 0=A half0, 1=A half1, 2=B half0, 3=B half1  (into buffer of tile t)
    auto stage_H = [&](int t, int h) {
        __bf16* base = lds + (size_t)(t & 1) * 32768 + (size_t)(h >> 1) * 16384;
        if (h & 2) stage_half(B, base, nHalf0 + (h & 1), t, h & 1);
        else       stage_half(A, base, mHalf0 + (h & 1), t, h & 1);
    };

    f32x4 acc[8][4];
#pragma unroll
    for (int i = 0; i < 8; ++i)
#pragma unroll
        for (int j = 0; j < 4; ++j)
            acc[i][j] = 0.0f;

    bf16x8 Af[8][2];
    bf16x8 Bf[2][2];

#define LDA(buf, mi, kb) (*(const bf16x8*)((buf) + (((wm * 8 + (mi)) * 2 + (kb)) * 512 + lane * 8)))
#define LDB(buf, ni, kb) (*(const bf16x8*)((buf) + (((wn * 4 + (ni)) * 2 + (kb)) * 512 + lane * 8)))

    // Prologue (FIFO order matters): tile0 all 4 halves, then A0(1),A1(1).
    stage_H(0, 0); stage_H(0, 1); stage_H(0, 2); stage_H(0, 3);
    stage_H(1, 0); stage_H(1, 1);
    VMCNT(4);                          // tile0 retired; {A0,A1}(1) in flight
    BAR();
    {   // pre-read A03(0)
        const __bf16* lA0 = lds;
#pragma unroll
        for (int mi = 0; mi < 4; ++mi) { Af[mi][0] = LDA(lA0, mi, 0); Af[mi][1] = LDA(lA0, mi, 1); }
    }

    for (int t = 0; t < NT; ++t) {
        const __bf16* lA  = lds + (size_t)(t & 1) * 32768;
        const __bf16* lB  = lA + 16384;
        const __bf16* lAn = lds + (size_t)((t + 1) & 1) * 32768;

        // ---- p0: read B01; stage B0(t+1); Q0 = A03*B01
#pragma unroll
        for (int ni = 0; ni < 2; ++ni) { Bf[ni][0] = LDB(lB, ni, 0); Bf[ni][1] = LDB(lB, ni, 1); }
        __builtin_amdgcn_sched_barrier(0);
        if (t < NT - 1) stage_H(t + 1, 2);
        BAR();
        __builtin_amdgcn_s_setprio(1);
#pragma unroll
        for (int kb = 0; kb < 2; ++kb)
#pragma unroll
            for (int mi = 0; mi < 4; ++mi)
#pragma unroll
                for (int ni = 0; ni < 2; ++ni)
                    acc[mi][ni] = __builtin_amdgcn_mfma_f32_16x16x32_bf16(Af[mi][kb], Bf[ni][kb], acc[mi][ni], 0, 0, 0);
        __builtin_amdgcn_s_setprio(0);
        BAR();

        // ---- p1: read A47; stage B1(t+1); Q1 = A47*B01
#pragma unroll
        for (int mi = 4; mi < 8; ++mi) { Af[mi][0] = LDA(lA, mi, 0); Af[mi][1] = LDA(lA, mi, 1); }
        __builtin_amdgcn_sched_barrier(0);
        if (t < NT - 1) stage_H(t + 1, 3);
        BAR();
        __builtin_amdgcn_s_setprio(1);
#pragma unroll
        for (int kb = 0; kb < 2; ++kb)
#pragma unroll
            for (int mi = 4; mi < 8; ++mi)
#pragma unroll
                for (int ni = 0; ni < 2; ++ni)
                    acc[mi][ni] = __builtin_amdgcn_mfma_f32_16x16x32_bf16(Af[mi][kb], Bf[ni][kb], acc[mi][ni], 0, 0, 0);
        __builtin_amdgcn_s_setprio(0);
        BAR();

        // ---- p2: read B23 (overwrite Bf); stage A0(t+2); Q2 = A03*B23; vmcnt
#pragma unroll
        for (int ni = 0; ni < 2; ++ni) { Bf[ni][0] = LDB(lB, ni + 2, 0); Bf[ni][1] = LDB(lB, ni + 2, 1); }
        __builtin_amdgcn_sched_barrier(0);
        if (t < NT - 2) stage_H(t + 2, 0);
        BAR();
        __builtin_amdgcn_s_setprio(1);
#pragma unroll
        for (int kb = 0; kb < 2; ++kb)
#pragma unroll
            for (int mi = 0; mi < 4; ++mi)
#pragma unroll
                for (int nj = 0; nj < 2; ++nj)
                    acc[mi][nj + 2] = __builtin_amdgcn_mfma_f32_16x16x32_bf16(Af[mi][kb], Bf[nj][kb], acc[mi][nj + 2], 0, 0, 0);
        __builtin_amdgcn_s_setprio(0);
        if (t < NT - 2)       VMCNT(6);   // A halves of tile t+1 published
        else if (t == NT - 2) VMCNT(4);
        BAR();

        // ---- p3: read A03(t+1) ahead; stage A1(t+2); Q3 = A47*B23; vmcnt
        if (t < NT - 1) {
#pragma unroll
            for (int mi = 0; mi < 4; ++mi) { Af[mi][0] = LDA(lAn, mi, 0); Af[mi][1] = LDA(lAn, mi, 1); }
        }
        __builtin_amdgcn_sched_barrier(0);
        if (t < NT - 2) stage_H(t + 2, 1);
        BAR();
        __builtin_amdgcn_s_setprio(1);
#pragma unroll
        for (int kb = 0; kb < 2; ++kb)
#pragma unroll
            for (int mi = 4; mi < 8; ++mi)
#pragma unroll
                for (int nj = 0; nj < 2; ++nj)
                    acc[mi][nj + 2] = __builtin_amdgcn_mfma_f32_16x16x32_bf16(Af[mi][kb], Bf[nj][kb], acc[mi][nj + 2], 0, 0, 0);
        __builtin_amdgcn_s_setprio(0);
        if (t < NT - 2)       VMCNT(4);   // B halves of tile t+1 published
        else if (t == NT - 2) VMCNT(0);
        BAR();
    }

    // Epilogue: C/D layout col=lane&15, row=(lane>>4)*4+reg
#pragma unroll
    for (int mi = 0; mi < 8; ++mi)
#pragma unroll
        for (int ni = 0; ni < 4; ++ni) {
            const int col = nBase + wn * 64 + ni * 16 + lr;
#pragma unroll
            for (int r = 0; r < 4; ++r) {
                const int row = mBase + wm * 128 + mi * 16 + (lane >> 4) * 4 + r;
                C[(size_t)row * N_DIM + col] = (float)(__bf16)acc[mi][ni][r];
            }
        }
#undef LDA
#undef LDB
}

extern "C" void kernel_launch(void* const* d_in, const int* in_sizes, int n_in,
                              void* d_out, int out_size, void* d_ws, size_t ws_size,
                              hipStream_t stream)
{
    const float* x       = (const float*)d_in[0];
    const int*   qweight = (const int*)d_in[1];
    const float* qscale  = (const float*)d_in[2];
    const int*   qzeros  = (const int*)d_in[3];
    float*       out     = (float*)d_out;

    __bf16* W  = (__bf16*)d_ws;
    __bf16* xb = (__bf16*)((char*)d_ws + (size_t)N_DIM * K_DIM * sizeof(__bf16));

    {
        int total = OUT_F * PACKED;
        dequant_kernel<<<(total + 255) / 256, 256, 0, stream>>>(qweight, qscale, qzeros, W);
    }
    {
        int nch = (M_DIM * K_DIM) / 8;
        cvt_kernel<<<(nch + 255) / 256, 256, 0, stream>>>(x, xb, nch);
    }
    {
        (void)hipFuncSetAttribute((const void*)gemm_kernel,
                                  hipFuncAttributeMaxDynamicSharedMemorySize, 131072);
        dim3 grid((M_DIM / BM) * (N_DIM / BN));   // 512 blocks
        gemm_kernel<<<grid, 512, 131072, stream>>>(xb, W, out);
    }
}